// Round 15
// baseline (13.479 us; speedup 1.0000x reference)
//
#include <hip/hip_runtime.h>

#define KAPPA 0.276f
#define NTRI 8256        // 128*129/2 packed floats per batch
#define BATCH 1024
#define SCALE (1.0f / (128.0f * 1024.0f))   // /trace2(=128), /B for mean

// dst lane i <- src lane (i+2)&15 within each 16-lane row: row_ror:14 (0x12E).
// Implements B-partner kB(k) = (k&0x70)|((k+2)&15) on register data; applying
// it to the diagonal-masked own value also inherits the partner's mask.
__device__ __forceinline__ float rotl2(float v) {
    return __int_as_float(__builtin_amdgcn_mov_dpp(__float_as_int(v),
                                                   0x12E, 0xF, 0xF, false));
}

__global__ __launch_bounds__(512) void trace_kernel(const float* __restrict__ net_out,
                                                    const float* __restrict__ U1,
                                                    float* __restrict__ ws) {
    const int bid = blockIdx.x;               // one block per batch
    // XCD-aware swizzle: XCD x (dispatch round-robins bid&7) owns contiguous
    // batches [128x, 128x+128) for L2 locality.
    const int xcd = bid & 7;
    const int b   = (xcd << 7) + (bid >> 3);
    const int tid = threadIdx.x;
    const int w   = tid >> 6;                 // wave 0..7 = row class r
    const int l   = tid & 63;                 // lane owns elements k=l, k=l+64 per row
    const int r   = w;                        // rows r, r+8, ..., r+120

    const float* __restrict__ X = net_out + (size_t)b * NTRI;
    const float* __restrict__ U = U1 + (size_t)b * 128;

    const int kAh = (l + 80) & 127;           // high-half A-partner column (loop-inv)

    // ---- phase 1: issue ALL loads (own + A-partners; partners are L1 hits
    //      in the same 256B row windows; no DS ops anywhere in the hot path) ----
    float vlo[8], alo[8], vx[8], vxh[8], ax[8], axh[8];
    {
        int i = r, o = (r * (r + 1)) >> 1;
        #pragma unroll
        for (int t = 0; t < 8; ++t) {
            vlo[t] = X[o + l];
            alo[t] = X[o + l + 16];
            o += (i << 3) + 36;               // tri(i+8)-tri(i)
            i += 8;
        }
    }
    {
        int i = r + 64, o = ((r + 64) * (r + 65)) >> 1;
        #pragma unroll
        for (int t = 0; t < 8; ++t) {
            vx[t]  = X[o + l];
            vxh[t] = X[o + l + 64];
            ax[t]  = X[o + l + 16];
            axh[t] = X[o + kAh];
            o += (i << 3) + 36;
            i += 8;
        }
    }

    // per-lane coefficients (site of element k is k>>1); HW cos (rel err ~1e-5)
    const float m2k = -2.0f * KAPPA;
    const float cAl = m2k * __cosf(U[(l >> 1)]);
    const float cAh = m2k * __cosf(U[32 + (l >> 1)]);
    const float cBl = m2k * __cosf(U[64 + (l >> 1)]);
    const float cBh = m2k * __cosf(U[96 + (l >> 1)]);

    float sq = 0.f, hAl = 0.f, hBl = 0.f, hAh = 0.f, hBh = 0.f;

    // ---- phase 2: consume. Same predicates the shfl-inheritance encoded
    //      (lane algebra verified absmax 0.0 across R11-R14) ----
    #pragma unroll
    for (int t = 0; t < 8; ++t) {             // rows i = r..r+56: low half only
        const int i = r + (t << 3);
        float x = (l      <= i) ? vlo[t] : 0.f;
        float a = (l + 16 <= i) ? alo[t] : 0.f;
        float bb = rotl2(x);                  // B-partner via DPP (mask inherited)
        sq  = fmaf(x, x,  sq);
        hAl = fmaf(x, a,  hAl);
        hBl = fmaf(x, bb, hBl);
    }
    #pragma unroll
    for (int t = 0; t < 8; ++t) {             // rows i = r+64..r+120: both halves
        const int i = r + 64 + (t << 3);
        float x  = vx[t];                     // k=l <= 63 < i: always valid
        float xh = (l + 64 <= i) ? vxh[t] : 0.f;
        float a  = (l + 16 <= i) ? ax[t]  : 0.f;
        float ah = (kAh    <= i) ? axh[t] : 0.f;
        float bb = rotl2(x);                  // always valid (kB <= 63 < i)
        float bh = rotl2(xh);                 // mask inherited
        sq  = fmaf(x,  x,  sq);
        sq  = fmaf(xh, xh, sq);
        hAl = fmaf(x,  a,  hAl);
        hBl = fmaf(x,  bb, hBl);
        hAh = fmaf(xh, ah, hAh);
        hBh = fmaf(xh, bh, hBh);
    }

    float val = sq + cAl * hAl + cAh * hAh + cBl * hBl + cBh * hBh;

    // wave reduce (only DS use in the kernel)
    #pragma unroll
    for (int off = 32; off > 0; off >>= 1)
        val += __shfl_down(val, off, 64);

    __shared__ float red[8];
    if (l == 0) red[w] = val;
    __syncthreads();
    if (tid == 0) {
        float p = 0.f;
        #pragma unroll
        for (int j = 0; j < 8; ++j) p += red[j];
        ws[bid] = p;
    }
}

__global__ __launch_bounds__(1024) void reduce_kernel(const float* __restrict__ ws,
                                                      float* __restrict__ out) {
    const int tid = threadIdx.x;
    float v = ws[tid];
    #pragma unroll
    for (int off = 32; off > 0; off >>= 1)
        v += __shfl_down(v, off, 64);
    __shared__ float red[16];
    if ((tid & 63) == 0) red[tid >> 6] = v;
    __syncthreads();
    if (tid < 64) {
        float s = (tid < 16) ? red[tid] : 0.f;
        #pragma unroll
        for (int off = 8; off > 0; off >>= 1)
            s += __shfl_down(s, off, 64);
        if (tid == 0) out[0] = s * SCALE;
    }
}

extern "C" void kernel_launch(void* const* d_in, const int* in_sizes, int n_in,
                              void* d_out, int out_size, void* d_ws, size_t ws_size,
                              hipStream_t stream) {
    const float* net_out = (const float*)d_in[0];  // (1024, 8256) fp32
    const float* U1      = (const float*)d_in[1];  // (1024, 2, 8, 8) fp32
    float* out = (float*)d_out;                    // scalar fp32
    float* ws  = (float*)d_ws;                     // >= BATCH floats

    trace_kernel<<<BATCH, 512, 0, stream>>>(net_out, U1, ws);
    reduce_kernel<<<1, 1024, 0, stream>>>(ws, out);
}

// Round 16
// 11.758 us; speedup vs baseline: 1.1464x; 1.1464x over previous
//
#include <hip/hip_runtime.h>

#define KAPPA 0.276f
#define NTRI 8256        // 128*129/2 packed floats per batch
#define BATCH 1024
#define SCALE (1.0f / (128.0f * 1024.0f))   // /trace2(=128), /B for mean

// Empirical DPP convention validated R11-R14 (absmax 0.0): ctrl 0x120+N => dst d <- src (d+(16-N))&15.
__device__ __forceinline__ float ror4(float v) {   // dst d <- src (d+4)&15 within 16-lane row
    return __int_as_float(__builtin_amdgcn_mov_dpp(__float_as_int(v), 0x12C, 0xF, 0xF, false));
}
__device__ __forceinline__ float qp1(float v) {    // quad_perm[1,2,3,0]: dst q <- src (q+1)&3
    return __int_as_float(__builtin_amdgcn_mov_dpp(__float_as_int(v), 0x39, 0xF, 0xF, false));
}

__global__ __launch_bounds__(512) void trace_kernel(const float* __restrict__ net_out,
                                                    const float* __restrict__ U1,
                                                    float* __restrict__ ws) {
    const int bid = blockIdx.x;               // one block per batch
    const int xcd = bid & 7;                  // XCD-aware swizzle (L2 locality)
    const int b   = (xcd << 7) + (bid >> 3);
    const int tid = threadIdx.x;
    const int w   = tid >> 6;                 // wave 0..7
    const int l   = tid & 63;
    const int m   = l & 15;                   // lane-in-row (16-lane rows)
    const int g   = l >> 4;                   // row group 0..3

    const float* __restrict__ X = net_out + (size_t)b * NTRI;
    const float* __restrict__ U = U1 + (size_t)b * 128;

    // rows handled by this lane's 16-lane group
    const int r0 = w + (g << 3);              // low rows set 1: i = r0 (<32)
    const int r1 = r0 + 32;                   // low set 2 (<64)
    const int r2 = r0 + 64;                   // high set 1
    const int r3 = r0 + 96;                   // high set 2
    const int t0 = (r0 * (r0 + 1)) >> 1;
    const int t1 = (r1 * (r1 + 1)) >> 1;
    const int t2 = (r2 * (r2 + 1)) >> 1;
    const int t3 = (r3 * (r3 + 1)) >> 1;
    const int c0 = m << 2;                    // base column of this lane's quad

    // ---- phase 1: ALL 6 vector loads issued up front (max MLP) ----
    const float4 L1  = *(const float4*)(X + t0 + c0);
    const float4 L2  = *(const float4*)(X + t1 + c0);
    const float4 H1P = *(const float4*)(X + t2 + c0);
    const float4 H1Q = *(const float4*)(X + t2 + 64 + c0);
    const float4 H2P = *(const float4*)(X + t3 + c0);
    const float4 H2Q = *(const float4*)(X + t3 + 64 + c0);

    const bool mlt12 = (m < 12);

    float sq = 0.f;
    float hAp01 = 0.f, hAp23 = 0.f, hAq01 = 0.f, hAq23 = 0.f;
    float hBp01 = 0.f, hBp23 = 0.f, hBq01 = 0.f, hBq23 = 0.f;

    // ---- low rows: cols 0..63 only; A-partner cols c+16 valid only for m<12 ----
    {
        // set 1 (i = r0)
        float x0 = (c0     <= r0) ? L1.x : 0.f;
        float x1 = (c0 + 1 <= r0) ? L1.y : 0.f;
        float x2 = (c0 + 2 <= r0) ? L1.z : 0.f;
        float x3 = (c0 + 3 <= r0) ? L1.w : 0.f;
        float a0 = mlt12 ? ror4(x0) : 0.f;
        float a1 = mlt12 ? ror4(x1) : 0.f;
        float a2 = mlt12 ? ror4(x2) : 0.f;
        float a3 = mlt12 ? ror4(x3) : 0.f;
        sq    += x0*x0 + x1*x1 + x2*x2 + x3*x3;
        hAp01 = fmaf(x0, a0, fmaf(x1, a1, hAp01));
        hAp23 = fmaf(x2, a2, fmaf(x3, a3, hAp23));
        hBp01 = fmaf(x0, x2, fmaf(x1, x3, hBp01));          // b0=x2, b1=x3
        hBp23 = fmaf(x2, qp1(x0), fmaf(x3, qp1(x1), hBp23)); // b2,b3 via quad rotate
        // set 2 (i = r1)
        float y0 = (c0     <= r1) ? L2.x : 0.f;
        float y1 = (c0 + 1 <= r1) ? L2.y : 0.f;
        float y2 = (c0 + 2 <= r1) ? L2.z : 0.f;
        float y3 = (c0 + 3 <= r1) ? L2.w : 0.f;
        float e0 = mlt12 ? ror4(y0) : 0.f;
        float e1 = mlt12 ? ror4(y1) : 0.f;
        float e2 = mlt12 ? ror4(y2) : 0.f;
        float e3 = mlt12 ? ror4(y3) : 0.f;
        sq    += y0*y0 + y1*y1 + y2*y2 + y3*y3;
        hAp01 = fmaf(y0, e0, fmaf(y1, e1, hAp01));
        hAp23 = fmaf(y2, e2, fmaf(y3, e3, hAp23));
        hBp01 = fmaf(y0, y2, fmaf(y1, y3, hBp01));
        hBp23 = fmaf(y2, qp1(y0), fmaf(y3, qp1(y1), hBp23));
    }

    // ---- high rows: P (cols 0..63, always valid) + Q (cols 64..127, masked) ----
    #pragma unroll
    for (int s = 0; s < 2; ++s) {
        const int   i  = s ? r3 : r2;
        const float4 P = s ? H2P : H1P;
        const float4 Q = s ? H2Q : H1Q;
        const int   cq = c0 + 64;
        float p0 = P.x, p1 = P.y, p2 = P.z, p3 = P.w;      // c<=63 < i: unmasked
        float q0 = (cq     <= i) ? Q.x : 0.f;
        float q1 = (cq + 1 <= i) ? Q.y : 0.f;
        float q2 = (cq + 2 <= i) ? Q.z : 0.f;
        float q3 = (cq + 3 <= i) ? Q.w : 0.f;

        // A-partner: +16 cols mod 128 = ror4 with P<->Q swap at the 16-boundary
        float rp0 = ror4(p0), rp1 = ror4(p1), rp2 = ror4(p2), rp3 = ror4(p3);
        float rq0 = ror4(q0), rq1 = ror4(q1), rq2 = ror4(q2), rq3 = ror4(q3);
        float aP0 = mlt12 ? rp0 : rq0, aP1 = mlt12 ? rp1 : rq1;
        float aP2 = mlt12 ? rp2 : rq2, aP3 = mlt12 ? rp3 : rq3;
        float aQ0 = mlt12 ? rq0 : rp0, aQ1 = mlt12 ? rq1 : rp1;
        float aQ2 = mlt12 ? rq2 : rp2, aQ3 = mlt12 ? rq3 : rp3;

        sq += p0*p0 + p1*p1 + p2*p2 + p3*p3;
        sq += q0*q0 + q1*q1 + q2*q2 + q3*q3;
        hAp01 = fmaf(p0, aP0, fmaf(p1, aP1, hAp01));
        hAp23 = fmaf(p2, aP2, fmaf(p3, aP3, hAp23));
        hAq01 = fmaf(q0, aQ0, fmaf(q1, aQ1, hAq01));
        hAq23 = fmaf(q2, aQ2, fmaf(q3, aQ3, hAq23));
        hBp01 = fmaf(p0, p2, fmaf(p1, p3, hBp01));
        hBp23 = fmaf(p2, qp1(p0), fmaf(p3, qp1(p1), hBp23));
        hBq01 = fmaf(q0, q2, fmaf(q1, q3, hBq01));
        hBq23 = fmaf(q2, qp1(q0), fmaf(q3, qp1(q1), hBq23));
    }

    // ---- epilogue: per-lane coefficients (site of col c is c>>1) ----
    const float m2k = -2.0f * KAPPA;
    const int   m2  = m << 1;
    float hop = __cosf(U[m2])      * hAp01 + __cosf(U[m2 + 1])      * hAp23
              + __cosf(U[32 + m2]) * hAq01 + __cosf(U[32 + m2 + 1]) * hAq23
              + __cosf(U[64 + m2]) * hBp01 + __cosf(U[64 + m2 + 1]) * hBp23
              + __cosf(U[96 + m2]) * hBq01 + __cosf(U[96 + m2 + 1]) * hBq23;
    float val = fmaf(m2k, hop, sq);

    // wave reduce
    #pragma unroll
    for (int off = 32; off > 0; off >>= 1)
        val += __shfl_down(val, off, 64);

    __shared__ float red[8];
    if (l == 0) red[w] = val;
    __syncthreads();
    if (tid == 0) {
        float p = 0.f;
        #pragma unroll
        for (int j = 0; j < 8; ++j) p += red[j];
        ws[bid] = p;
    }
}

__global__ __launch_bounds__(1024) void reduce_kernel(const float* __restrict__ ws,
                                                      float* __restrict__ out) {
    const int tid = threadIdx.x;
    float v = ws[tid];
    #pragma unroll
    for (int off = 32; off > 0; off >>= 1)
        v += __shfl_down(v, off, 64);
    __shared__ float red[16];
    if ((tid & 63) == 0) red[tid >> 6] = v;
    __syncthreads();
    if (tid < 64) {
        float s = (tid < 16) ? red[tid] : 0.f;
        #pragma unroll
        for (int off = 8; off > 0; off >>= 1)
            s += __shfl_down(s, off, 64);
        if (tid == 0) out[0] = s * SCALE;
    }
}

extern "C" void kernel_launch(void* const* d_in, const int* in_sizes, int n_in,
                              void* d_out, int out_size, void* d_ws, size_t ws_size,
                              hipStream_t stream) {
    const float* net_out = (const float*)d_in[0];  // (1024, 8256) fp32
    const float* U1      = (const float*)d_in[1];  // (1024, 2, 8, 8) fp32
    float* out = (float*)d_out;                    // scalar fp32
    float* ws  = (float*)d_ws;                     // >= BATCH floats

    trace_kernel<<<BATCH, 512, 0, stream>>>(net_out, U1, ws);
    reduce_kernel<<<1, 1024, 0, stream>>>(ws, out);
}